// Round 3
// baseline (377.073 us; speedup 1.0000x reference)
//
#include <hip/hip_runtime.h>
#include <math.h>

#define NUM_BINS 15
#define CCLS 100
#define GRID 2048
#define BLOCK 256

// Select element i (0..3) of a float4 with a cndmask tree (no scratch).
__device__ __forceinline__ float pick4(float4 v, int i) {
    float lo = (i & 1) ? v.y : v.x;
    float hi = (i & 1) ? v.w : v.z;
    return (i & 2) ? hi : lo;
}

// One wave = 4 groups of 16 lanes; group handles rows r and r+4 per chunk
// (8 rows/chunk/wave). Three butterfly chains per row: max(x), sum(exp x),
// and sel-exp(x_label) (label logit picked from registers — NO gather).
// Per-bin accumulation is a register: lane s owns bin s, dacc += diff.
// NO LDS and NO atomics anywhere in the hot loop.
__global__ __launch_bounds__(BLOCK) void ece_fused(
    const float* __restrict__ logits,
    const int* __restrict__ labels,
    float* __restrict__ ws,   // [0..14]: sum(conf-pred) per bin; int ticket at ws[48]
    float* __restrict__ out,
    int n_rows)
{
    __shared__ float s_part[(BLOCK / 64) * 16];
    __shared__ int s_last;

    const int tid  = threadIdx.x;
    const int lane = tid & 63;
    const int g    = lane >> 4;      // group 0..3
    const int s    = lane & 15;      // sublane in group
    const int wave = tid >> 6;
    const int gwave = blockIdx.x * (BLOCK / 64) + wave;
    const int nwav  = GRID * (BLOCK / 64);
    const int n_chunks = n_rows >> 3;
    const bool hasb = (s < 9);       // cols 64..99 = 9 float4

    float dacc = 0.f;                // register accumulator: bin == s

    for (int chunk = gwave; chunk < n_chunks; chunk += nwav) {
        const int r0 = (chunk << 3) + g;
        const int r1 = r0 + 4;
        const float* p0 = logits + (size_t)r0 * CCLS;
        const float* p1 = logits + (size_t)r1 * CCLS;

        // all loads issued up front; labels broadcast within group (1 line)
        float4 a0 = *(const float4*)(p0 + 4 * s);
        float4 a1 = *(const float4*)(p1 + 4 * s);
        float4 b0 = a0, b1 = a1;
        if (hasb) {
            b0 = *(const float4*)(p0 + 64 + 4 * s);
            b1 = *(const float4*)(p1 + 64 + 4 * s);
        }
        const int lab0 = labels[r0];
        const int lab1 = labels[r1];

        // per-lane partials: max, sum-exp (logits ~N(0,1): exp safe in fp32)
        float m0 = fmaxf(fmaxf(a0.x, a0.y), fmaxf(a0.z, a0.w));
        float m1 = fmaxf(fmaxf(a1.x, a1.y), fmaxf(a1.z, a1.w));
        float e0 = __expf(a0.x) + __expf(a0.y) + __expf(a0.z) + __expf(a0.w);
        float e1 = __expf(a1.x) + __expf(a1.y) + __expf(a1.z) + __expf(a1.w);
        if (hasb) {
            m0 = fmaxf(m0, fmaxf(fmaxf(b0.x, b0.y), fmaxf(b0.z, b0.w)));
            m1 = fmaxf(m1, fmaxf(fmaxf(b1.x, b1.y), fmaxf(b1.z, b1.w)));
            e0 += __expf(b0.x) + __expf(b0.y) + __expf(b0.z) + __expf(b0.w);
            e1 += __expf(b1.x) + __expf(b1.y) + __expf(b1.z) + __expf(b1.w);
        }

        // label logit from registers: owning lane contributes exp(x_lab)
        const int la0 = lab0 >> 2, lo0 = lab0 & 3;
        const int la1 = lab1 >> 2, lo1 = lab1 & 3;
        float t0 = 0.f, t1 = 0.f;
        if (la0 == s)           t0 = __expf(pick4(a0, lo0));
        else if (la0 - 16 == s) t0 = __expf(pick4(b0, lo0));   // la0-16 <= 8 < 9, b0 valid
        if (la1 == s)           t1 = __expf(pick4(a1, lo1));
        else if (la1 - 16 == s) t1 = __expf(pick4(b1, lo1));

        // 16-lane butterfly, 6 interleaved chains, 4 steps
        #pragma unroll
        for (int off = 8; off >= 1; off >>= 1) {
            m0 = fmaxf(m0, __shfl_xor(m0, off));
            m1 = fmaxf(m1, __shfl_xor(m1, off));
            e0 += __shfl_xor(e0, off);
            e1 += __shfl_xor(e1, off);
            t0 += __shfl_xor(t0, off);
            t1 += __shfl_xor(t1, off);
        }

        // every lane of the group now has m,e,t; lane s==bin accumulates
        const float inv0 = 1.0f / e0, inv1 = 1.0f / e1;
        const float conf0 = __expf(m0) * inv0, conf1 = __expf(m1) * inv1;
        const float diff0 = conf0 - t0 * inv0;
        const float diff1 = conf1 - t1 * inv1;
        int bin0 = (int)(conf0 * (float)NUM_BINS); bin0 = bin0 > NUM_BINS - 1 ? NUM_BINS - 1 : bin0;
        int bin1 = (int)(conf1 * (float)NUM_BINS); bin1 = bin1 > NUM_BINS - 1 ? NUM_BINS - 1 : bin1;
        dacc += (s == bin0) ? diff0 : 0.f;
        dacc += (s == bin1) ? diff1 : 0.f;
    }

    // tail rows (n_rows % 8) — global wave 0, one row per group
    if (gwave == 0) {
        for (int r = (n_chunks << 3) + g; r < n_rows; r += 4) {
            const float* p = logits + (size_t)r * CCLS;
            float4 a = *(const float4*)(p + 4 * s);
            float4 b = a;
            if (hasb) b = *(const float4*)(p + 64 + 4 * s);
            const int lab = labels[r];
            float m = fmaxf(fmaxf(a.x, a.y), fmaxf(a.z, a.w));
            float e = __expf(a.x) + __expf(a.y) + __expf(a.z) + __expf(a.w);
            if (hasb) {
                m = fmaxf(m, fmaxf(fmaxf(b.x, b.y), fmaxf(b.z, b.w)));
                e += __expf(b.x) + __expf(b.y) + __expf(b.z) + __expf(b.w);
            }
            const int la = lab >> 2, lo = lab & 3;
            float t = 0.f;
            if (la == s)           t = __expf(pick4(a, lo));
            else if (la - 16 == s) t = __expf(pick4(b, lo));
            #pragma unroll
            for (int off = 8; off >= 1; off >>= 1) {
                m = fmaxf(m, __shfl_xor(m, off));
                e += __shfl_xor(e, off);
                t += __shfl_xor(t, off);
            }
            const float inv = 1.0f / e;
            const float conf = __expf(m) * inv;
            const float diff = conf - t * inv;
            int bin = (int)(conf * (float)NUM_BINS); bin = bin > NUM_BINS - 1 ? NUM_BINS - 1 : bin;
            dacc += (s == bin) ? diff : 0.f;
        }
    }

    // fold groups: lanes s, s+16, s+32, s+48 all hold bin-s partials
    dacc += __shfl_xor(dacc, 16);
    dacc += __shfl_xor(dacc, 32);
    if (lane < 16) s_part[wave * 16 + lane] = dacc;
    __syncthreads();

    if (tid < NUM_BINS)
        atomicAdd(&ws[tid], s_part[tid] + s_part[16 + tid] + s_part[32 + tid] + s_part[48 + tid]);
    __syncthreads();

    // ticket: last block computes ECE = sum_b |ws[b]| / N
    if (tid == 0) {
        __threadfence();
        const int t = atomicAdd((int*)(ws + 48), 1);
        s_last = (t == GRID - 1) ? 1 : 0;
    }
    __syncthreads();
    if (s_last && tid < 64) {
        __threadfence();
        float contrib = 0.f;
        if (tid < NUM_BINS) {
            const float v = __hip_atomic_load(&ws[tid], __ATOMIC_RELAXED, __HIP_MEMORY_SCOPE_AGENT);
            contrib = fabsf(v);
        }
        #pragma unroll
        for (int off = 32; off >= 1; off >>= 1)
            contrib += __shfl_xor(contrib, off);
        if (tid == 0) out[0] = contrib / (float)n_rows;
    }
}

extern "C" void kernel_launch(void* const* d_in, const int* in_sizes, int n_in,
                              void* d_out, int out_size, void* d_ws, size_t ws_size,
                              hipStream_t stream)
{
    const float* logits = (const float*)d_in[0];
    const int*   labels = (const int*)d_in[1];
    float* out = (float*)d_out;
    float* ws  = (float*)d_ws;

    const int n_rows = in_sizes[1];

    // ws re-poisoned to 0xAA before every timed launch — zero accumulators+ticket.
    hipMemsetAsync(ws, 0, 64 * sizeof(float), stream);

    ece_fused<<<dim3(GRID), dim3(BLOCK), 0, stream>>>(logits, labels, ws, out, n_rows);
}